// Round 6
// baseline (151.638 us; speedup 1.0000x reference)
//
#include <hip/hip_runtime.h>

#define HID 512
#define SEQ 4096
#define NB 32
#define BS 64
#define NSB 8          // s-blocks per batch row (persistent blocks)
#define CPB 8          // chunks per s-block
#define CH2 1026       // [m, den, num[1024]]

typedef __attribute__((ext_vector_type(8))) __bf16 bf16x8;
typedef __attribute__((ext_vector_type(16))) float f32x16;

__device__ __forceinline__ float tanh_fast(float v) {
    float e = __expf(2.f * v);
    return 1.f - __fdividef(2.f, e + 1.f);
}

// ---- Kernel 1: build W1_a in MFMA-fragment order (h-tile ht, k-slice ks):
//      w1af[((ht*32+ks)*64 + lane)*8 + j] = bf16(W1a[k=ks*16+(lane>>5)*8+j][h=ht*32+(lane&31)])
__global__ void build_w1af(const float* __restrict__ W1,
                           unsigned short* __restrict__ w1af) {
    __shared__ float tile[64][65];
    int t = threadIdx.x;
    int lane = t & 63;
    int r4 = t >> 6;            // 0..3
    int k0 = blockIdx.x * 64;
    int h0 = blockIdx.y * 64;
#pragma unroll
    for (int i = 0; i < 16; ++i) {
        int r = i * 4 + r4;     // k-row within tile
        tile[r][lane] = W1[(size_t)(HID + k0 + r) * HID + h0 + lane];
    }
    __syncthreads();
#pragma unroll
    for (int i = 0; i < 16; ++i) {
        int hr = i * 4 + r4;    // h-row
        int h = h0 + hr, k = k0 + lane;
        __bf16 bv = (__bf16)tile[lane][hr];
        int ht = h >> 5, hl = h & 31;
        int ks = k >> 4, g = (k >> 3) & 1, j = k & 7;
        size_t off = (((size_t)ht * 32 + ks) * 64 + g * 32 + hl) * 8 + j;
        w1af[off] = *(unsigned short*)&bv;
    }
}

// ---- Kernel 2: pre_part[b][kc][h] = sum_{k in kc-chunk} prev[b][k]*W1_h[k][h] ----
__global__ void pre_partial(const float* __restrict__ prev,
                            const float* __restrict__ W1,
                            float* __restrict__ pre_part) {
    __shared__ float pl[128];
    int kc = blockIdx.x;   // 0..3
    int b  = blockIdx.y;
    int t  = threadIdx.x;
    if (t < 128) pl[t] = prev[b * HID + kc * 128 + t];
    __syncthreads();
    int h0 = 2 * t;
    float ax = 0.f, ay = 0.f;
    for (int k = 0; k < 128; ++k) {
        float pv = pl[k];
        float2 wv = *(const float2*)(W1 + (size_t)(kc * 128 + k) * HID + h0);
        ax += pv * wv.x;
        ay += pv * wv.y;
    }
    float* dst = pre_part + ((size_t)b * 4 + kc) * HID + h0;
    dst[0] = ax; dst[1] = ay;
}

// ---- Kernel 3: persistent fused kernel.  grid (8 sblocks, 32 b) x 1024.
//      Per block: loop over 8 chunks of 64 s-rows with LDS ping-pong;
//      stage-issue(c+1) -> K-loop(c) -> softmax(c) -> fused ctx(c, online) ->
//      vmcnt + ds_write(c+1).  HBM fetch of c+1 hides under compute of c. ----
__global__ __launch_bounds__(1024, 4)
void score_ctx(const float* __restrict__ ann,
               const unsigned short* __restrict__ w1af,
               const float* __restrict__ pre_part,
               const float* __restrict__ b1,
               const float* __restrict__ W2,
               float* __restrict__ cout) {
    __shared__ unsigned short annA[BS * 512];   // 64 KiB each, XOR-swizzled bf16
    __shared__ unsigned short annB[BS * 512];
    __shared__ float pre_lds[512];
    __shared__ float w2_lds[512];
    __shared__ float red[16][64];
    __shared__ float p_lds[64];
    __shared__ float md[2];

    const int sb = blockIdx.x, b = blockIdx.y;
    const int t = threadIdx.x;
    const int wv = t >> 6;        // wave 0..15 -> h-tile wv (32 h's)
    const int lane = t & 63;
    const int sl = lane & 31;
    const int g = lane >> 5;

    if (t < 512) {
        float pp = b1[t];
#pragma unroll
        for (int kc = 0; kc < 4; ++kc)
            pp += pre_part[((size_t)b * 4 + kc) * HID + t];
        pre_lds[t] = pp;
    } else {
        w2_lds[t - 512] = W2[t - 512];
    }

    const float* abase = ann + ((size_t)b * SEQ + (size_t)sb * (CPB * BS)) * 512;

    float4 sf[8];   // in-flight staging regs (32 fp32), statically indexed
    // ---- prologue: stage chunk 0 into annA ----
    {
#pragma unroll
        for (int i = 0; i < 4; ++i) {
            int idx = t + i * 1024;
            const float4* src = (const float4*)(abase + (size_t)(idx >> 6) * 512 + (idx & 63) * 8);
            sf[2 * i] = src[0]; sf[2 * i + 1] = src[1];
        }
#pragma unroll
        for (int i = 0; i < 4; ++i) {
            int idx = t + i * 1024;
            int row = idx >> 6, k8 = (idx & 63) * 8;
            bf16x8 pk;
            pk[0] = (__bf16)sf[2*i].x;   pk[1] = (__bf16)sf[2*i].y;
            pk[2] = (__bf16)sf[2*i].z;   pk[3] = (__bf16)sf[2*i].w;
            pk[4] = (__bf16)sf[2*i+1].x; pk[5] = (__bf16)sf[2*i+1].y;
            pk[6] = (__bf16)sf[2*i+1].z; pk[7] = (__bf16)sf[2*i+1].w;
            unsigned boff = ((unsigned)(row * 512 + k8) * 2u) ^ ((unsigned)(row & 7) << 4);
            *(bf16x8*)((char*)annA + boff) = pk;
        }
    }
    __syncthreads();

    float m_run = -3.0e38f, d_run = 0.f, ctx = 0.f;
    const int col = t & 511, half = t >> 9;

    const unsigned short* wb = w1af + (size_t)wv * 16384 + (size_t)lane * 8;
    const unsigned be0 = (unsigned)(sl * 512 + g * 8) * 2u;
    const unsigned be1 = (unsigned)((32 + sl) * 512 + g * 8) * 2u;
    const unsigned swz = (unsigned)(sl & 7) << 4;

#pragma unroll 1
    for (int c = 0; c < CPB; ++c) {
        unsigned short* curb = (c & 1) ? annB : annA;
        unsigned short* nxtb = (c & 1) ? annA : annB;

        // issue-early: global loads for chunk c+1 (consumed after this chunk's compute)
        if (c < CPB - 1) {
            const float* ab = abase + (size_t)(c + 1) * BS * 512;
#pragma unroll
            for (int i = 0; i < 4; ++i) {
                int idx = t + i * 1024;
                const float4* src = (const float4*)(ab + (size_t)(idx >> 6) * 512 + (idx & 63) * 8);
                sf[2 * i] = src[0]; sf[2 * i + 1] = src[1];
            }
        }

        // ---- K-loop: h-tile wv (A from L2, coalesced 1KiB/instr), 2 s-tiles ----
        f32x16 acc0, acc1;
#pragma unroll
        for (int r = 0; r < 16; ++r) { acc0[r] = 0.f; acc1[r] = 0.f; }
#pragma unroll 2
        for (int ks = 0; ks < 32; ++ks) {
            bf16x8 a = *(const bf16x8*)(wb + ks * 512);
            bf16x8 bf0 = *(const bf16x8*)((const char*)curb + ((be0 + (unsigned)ks * 32u) ^ swz));
            bf16x8 bf1 = *(const bf16x8*)((const char*)curb + ((be1 + (unsigned)ks * 32u) ^ swz));
            acc0 = __builtin_amdgcn_mfma_f32_32x32x16_bf16(a, bf0, acc0, 0, 0, 0);
            acc1 = __builtin_amdgcn_mfma_f32_32x32x16_bf16(a, bf1, acc1, 0, 0, 0);
        }

        // epilogue: tanh + w2-dot over this wave's 32 h's
        float sp0 = 0.f, sp1 = 0.f;
#pragma unroll
        for (int r = 0; r < 16; ++r) {
            int h = wv * 32 + (r & 3) + 8 * (r >> 2) + 4 * g;
            float pr = pre_lds[h], w2v = w2_lds[h];
            sp0 += w2v * tanh_fast(acc0[r] + pr);
            sp1 += w2v * tanh_fast(acc1[r] + pr);
        }
        sp0 += __shfl_xor(sp0, 32);
        sp1 += __shfl_xor(sp1, 32);
        if (lane < 32) { red[wv][lane] = sp0; red[wv][32 + lane] = sp1; }
        __syncthreads();

        if (wv == 0) {   // full wave: 64 scores, chunk-local softmax
            float sc = 0.f;
#pragma unroll
            for (int q = 0; q < 16; ++q) sc += red[q][lane];
            float m = sc;
#pragma unroll
            for (int off = 32; off; off >>= 1) m = fmaxf(m, __shfl_xor(m, off));
            float p = __expf(sc - m);
            float d = p;
#pragma unroll
            for (int off = 32; off; off >>= 1) d += __shfl_xor(d, off);
            p_lds[lane] = p;
            if (lane == 0) { md[0] = m; md[1] = d; }
        }
        __syncthreads();

        // online merge + fused ctx numerator from the staged tile
        float m_c = md[0], d_c = md[1];
        float m_new = fmaxf(m_run, m_c);
        float sc_old = __expf(m_run - m_new);
        float sc_c = __expf(m_c - m_new);
        d_run = d_run * sc_old + d_c * sc_c;
        float na = 0.f;
        const char* cb8 = (const char*)curb;
#pragma unroll 8
        for (int s2 = 0; s2 < 32; ++s2) {
            int s = half * 32 + s2;
            unsigned boff = ((unsigned)(s * 512 + col) * 2u) ^ ((unsigned)(s & 7) << 4);
            unsigned short us = *(const unsigned short*)(cb8 + boff);
            na += p_lds[s] * __uint_as_float((unsigned)us << 16);
        }
        ctx = ctx * sc_old + na * sc_c;
        m_run = m_new;

        // write-late: drain staged regs into the other buffer
        if (c < CPB - 1) {
            __syncthreads();   // all waves done reading nxtb's old contents (chunk c-1)
#pragma unroll
            for (int i = 0; i < 4; ++i) {
                int idx = t + i * 1024;
                int row = idx >> 6, k8 = (idx & 63) * 8;
                bf16x8 pk;
                pk[0] = (__bf16)sf[2*i].x;   pk[1] = (__bf16)sf[2*i].y;
                pk[2] = (__bf16)sf[2*i].z;   pk[3] = (__bf16)sf[2*i].w;
                pk[4] = (__bf16)sf[2*i+1].x; pk[5] = (__bf16)sf[2*i+1].y;
                pk[6] = (__bf16)sf[2*i+1].z; pk[7] = (__bf16)sf[2*i+1].w;
                unsigned boff = ((unsigned)(row * 512 + k8) * 2u) ^ ((unsigned)(row & 7) << 4);
                *(bf16x8*)((char*)nxtb + boff) = pk;
            }
            __syncthreads();
        }
    }

    float* cb = cout + ((size_t)b * NSB + sb) * CH2;
    cb[2 + half * 512 + col] = ctx;
    if (t == 0) { cb[0] = m_run; cb[1] = d_run; }
}

// ---- Kernel 4: merge 8 s-block partials per batch row ----
__global__ void finalize_ctx(const float* __restrict__ cout,
                             float* __restrict__ out) {
    int b = blockIdx.x, t = threadIdx.x;   // 512 threads
    float ms[NSB];
    float M = -3.0e38f;
#pragma unroll
    for (int s = 0; s < NSB; ++s) {
        ms[s] = cout[((size_t)b * NSB + s) * CH2];
        M = fmaxf(M, ms[s]);
    }
    float D = 0.f, val = 0.f;
#pragma unroll
    for (int s = 0; s < NSB; ++s) {
        const float* cb = cout + ((size_t)b * NSB + s) * CH2;
        float e = __expf(ms[s] - M);
        D += e * cb[1];
        val += e * (cb[2 + t] + cb[2 + 512 + t]);
    }
    out[(size_t)b * 512 + t] = val / D;
}

extern "C" void kernel_launch(void* const* d_in, const int* in_sizes, int n_in,
                              void* d_out, int out_size, void* d_ws, size_t ws_size,
                              hipStream_t stream) {
    (void)in_sizes; (void)n_in; (void)out_size; (void)ws_size;
    const float* prev = (const float*)d_in[0];
    const float* ann  = (const float*)d_in[1];
    const float* W1   = (const float*)d_in[2];
    const float* b1   = (const float*)d_in[3];
    const float* W2   = (const float*)d_in[4];
    // b2 (d_in[5]) cancels in softmax; unused.
    float* out = (float*)d_out;

    char* ws = (char*)d_ws;
    unsigned short* w1af = (unsigned short*)ws;               // 512*512*2 = 524288 B
    float* pre_part = (float*)(ws + 524288);                  // 32*4*512*4 = 262144 B
    float* cout     = (float*)(ws + 524288 + 262144);         // 32*8*1026*4 = 1050624 B

    build_w1af<<<dim3(8, 8), dim3(256), 0, stream>>>(W1, w1af);
    pre_partial<<<dim3(4, NB), dim3(256), 0, stream>>>(prev, W1, pre_part);
    score_ctx<<<dim3(NSB, NB), dim3(1024), 0, stream>>>(ann, w1af, pre_part, b1, W2, cout);
    finalize_ctx<<<dim3(NB), dim3(512), 0, stream>>>(cout, out);
}

// Round 7
// 142.464 us; speedup vs baseline: 1.0644x; 1.0644x over previous
//
#include <hip/hip_runtime.h>

#define HID 512
#define SEQ 4096
#define NB 32
#define BS 128         // s-rows per chunk
#define NSB 8          // s-blocks per batch row (blocks)
#define CPB 4          // chunks per block (NSB*CPB*BS = SEQ)
#define CH2 1026       // [m, den, num[1024]]

typedef __attribute__((ext_vector_type(8))) __bf16 bf16x8;
typedef __attribute__((ext_vector_type(16))) float f32x16;

__device__ __forceinline__ float tanh_fast(float v) {
    float e = __expf(2.f * v);
    return 1.f - __fdividef(2.f, e + 1.f);
}

// ---- Kernel 1: build W1_a in MFMA-fragment order (h-tile ht, k-slice ks):
//      w1af[((ht*32+ks)*64 + lane)*8 + j] = bf16(W1a[k=ks*16+(lane>>5)*8+j][h=ht*32+(lane&31)])
__global__ void build_w1af(const float* __restrict__ W1,
                           unsigned short* __restrict__ w1af) {
    __shared__ float tile[64][65];
    int t = threadIdx.x;
    int lane = t & 63;
    int r4 = t >> 6;            // 0..3
    int k0 = blockIdx.x * 64;
    int h0 = blockIdx.y * 64;
#pragma unroll
    for (int i = 0; i < 16; ++i) {
        int r = i * 4 + r4;     // k-row within tile
        tile[r][lane] = W1[(size_t)(HID + k0 + r) * HID + h0 + lane];
    }
    __syncthreads();
#pragma unroll
    for (int i = 0; i < 16; ++i) {
        int hr = i * 4 + r4;    // h-row
        int h = h0 + hr, k = k0 + lane;
        __bf16 bv = (__bf16)tile[lane][hr];
        int ht = h >> 5, hl = h & 31;
        int ks = k >> 4, g = (k >> 3) & 1, j = k & 7;
        size_t off = (((size_t)ht * 32 + ks) * 64 + g * 32 + hl) * 8 + j;
        w1af[off] = *(unsigned short*)&bv;
    }
}

// ---- Kernel 2: pre_part[b][kc][h] = sum_{k in kc-chunk} prev[b][k]*W1_h[k][h] ----
__global__ void pre_partial(const float* __restrict__ prev,
                            const float* __restrict__ W1,
                            float* __restrict__ pre_part) {
    __shared__ float pl[128];
    int kc = blockIdx.x;   // 0..3
    int b  = blockIdx.y;
    int t  = threadIdx.x;
    if (t < 128) pl[t] = prev[b * HID + kc * 128 + t];
    __syncthreads();
    int h0 = 2 * t;
    float ax = 0.f, ay = 0.f;
    for (int k = 0; k < 128; ++k) {
        float pv = pl[k];
        float2 wv = *(const float2*)(W1 + (size_t)(kc * 128 + k) * HID + h0);
        ax += pv * wv.x;
        ay += pv * wv.y;
    }
    float* dst = pre_part + ((size_t)b * 4 + kc) * HID + h0;
    dst[0] = ax; dst[1] = ay;
}

// ---- Kernel 3: fused kernel, 2x4 wave tile.  grid (8 sb, 32 b) x 512 (8 waves).
//      Wave wv owns h-tiles 2wv,2wv+1 (64 h) x 4 s-tiles (128 s): 8 acc chains,
//      8 MFMAs per (2 A-loads + 4 B-reads).  Chunk = 128 s in one 128 KiB buffer. ----
__global__ __launch_bounds__(512, 2)
void score_ctx(const float* __restrict__ ann,
               const unsigned short* __restrict__ w1af,
               const float* __restrict__ pre_part,
               const float* __restrict__ b1,
               const float* __restrict__ W2,
               float* __restrict__ cout) {
    __shared__ unsigned short ann_lds[BS * 512];   // 128 KiB, XOR-swizzled bf16
    __shared__ float pre_lds[512];
    __shared__ float w2_lds[512];
    __shared__ float red[8][BS];
    __shared__ float p_lds[BS];
    __shared__ float md[2];

    const int sb = blockIdx.x, b = blockIdx.y;
    const int t = threadIdx.x;
    const int wv = t >> 6;        // 0..7
    const int lane = t & 63;
    const int sl = lane & 31;
    const int g = lane >> 5;

    {
        float pp = b1[t];
#pragma unroll
        for (int kc = 0; kc < 4; ++kc)
            pp += pre_part[((size_t)b * 4 + kc) * HID + t];
        pre_lds[t] = pp;
        w2_lds[t] = W2[t];
    }

    const float* abase0 = ann + ((size_t)b * SEQ + (size_t)sb * (CPB * BS)) * 512;

    float m_run = -3.0e38f, d_run = 0.f;
    float ctxa = 0.f, ctxb = 0.f;
    const int cp = (t & 255) * 2;     // even column owned by this thread
    const int h2 = t >> 8;            // row-half (0: s 0..63, 1: s 64..127)

    const unsigned short* wb0 = w1af + (size_t)(2 * wv) * 16384 + (size_t)lane * 8;
    const unsigned short* wb1 = wb0 + 16384;
    const unsigned swz = (unsigned)(sl & 7) << 4;
    const unsigned rb0 = (unsigned)(( 0 + sl) * 1024 + g * 16);
    const unsigned rb1 = (unsigned)((32 + sl) * 1024 + g * 16);
    const unsigned rb2 = (unsigned)((64 + sl) * 1024 + g * 16);
    const unsigned rb3 = (unsigned)((96 + sl) * 1024 + g * 16);

#pragma unroll 1
    for (int c = 0; c < CPB; ++c) {
        __syncthreads();   // previous chunk's readers done (also covers pre_lds init)

        // ---- stage chunk c: 128 rows x 512 -> bf16 LDS, swizzle ^((row&7)<<4) ----
        const float* ab = abase0 + (size_t)c * BS * 512;
#pragma unroll 4
        for (int i = 0; i < 16; ++i) {
            int idx = t + i * 512;
            int row = idx >> 6, k8 = (idx & 63) * 8;
            const float4* src = (const float4*)(ab + (size_t)row * 512 + k8);
            float4 f0 = src[0], f1 = src[1];
            bf16x8 pk;
            pk[0] = (__bf16)f0.x; pk[1] = (__bf16)f0.y;
            pk[2] = (__bf16)f0.z; pk[3] = (__bf16)f0.w;
            pk[4] = (__bf16)f1.x; pk[5] = (__bf16)f1.y;
            pk[6] = (__bf16)f1.z; pk[7] = (__bf16)f1.w;
            unsigned boff = ((unsigned)(row * 512 + k8) * 2u) ^ ((unsigned)(row & 7) << 4);
            *(bf16x8*)((char*)ann_lds + boff) = pk;
        }
        __syncthreads();

        // ---- K-loop: 8 acc chains, 8 MFMAs per ks ----
        f32x16 a00, a01, a02, a03, a10, a11, a12, a13;
#pragma unroll
        for (int r = 0; r < 16; ++r) {
            a00[r] = 0.f; a01[r] = 0.f; a02[r] = 0.f; a03[r] = 0.f;
            a10[r] = 0.f; a11[r] = 0.f; a12[r] = 0.f; a13[r] = 0.f;
        }
#pragma unroll 2
        for (int ks = 0; ks < 32; ++ks) {
            bf16x8 A0 = *(const bf16x8*)(wb0 + ks * 512);
            bf16x8 A1 = *(const bf16x8*)(wb1 + ks * 512);
            unsigned kb = (unsigned)ks * 32u;
            bf16x8 B0 = *(const bf16x8*)((const char*)ann_lds + ((rb0 + kb) ^ swz));
            bf16x8 B1 = *(const bf16x8*)((const char*)ann_lds + ((rb1 + kb) ^ swz));
            bf16x8 B2 = *(const bf16x8*)((const char*)ann_lds + ((rb2 + kb) ^ swz));
            bf16x8 B3 = *(const bf16x8*)((const char*)ann_lds + ((rb3 + kb) ^ swz));
            a00 = __builtin_amdgcn_mfma_f32_32x32x16_bf16(A0, B0, a00, 0, 0, 0);
            a10 = __builtin_amdgcn_mfma_f32_32x32x16_bf16(A1, B0, a10, 0, 0, 0);
            a01 = __builtin_amdgcn_mfma_f32_32x32x16_bf16(A0, B1, a01, 0, 0, 0);
            a11 = __builtin_amdgcn_mfma_f32_32x32x16_bf16(A1, B1, a11, 0, 0, 0);
            a02 = __builtin_amdgcn_mfma_f32_32x32x16_bf16(A0, B2, a02, 0, 0, 0);
            a12 = __builtin_amdgcn_mfma_f32_32x32x16_bf16(A1, B2, a12, 0, 0, 0);
            a03 = __builtin_amdgcn_mfma_f32_32x32x16_bf16(A0, B3, a03, 0, 0, 0);
            a13 = __builtin_amdgcn_mfma_f32_32x32x16_bf16(A1, B3, a13, 0, 0, 0);
        }

        // ---- epilogue: tanh + w2-dot over this wave's 64 h's, per s-tile ----
        float sp0 = 0.f, sp1 = 0.f, sp2 = 0.f, sp3 = 0.f;
#pragma unroll
        for (int r = 0; r < 16; ++r) {
            int hl = (r & 3) + 8 * (r >> 2) + 4 * g;
            int ha = wv * 64 + hl, hb = wv * 64 + 32 + hl;
            float pa = pre_lds[ha], wa = w2_lds[ha];
            float pb = pre_lds[hb], wbv = w2_lds[hb];
            sp0 += wa * tanh_fast(a00[r] + pa) + wbv * tanh_fast(a10[r] + pb);
            sp1 += wa * tanh_fast(a01[r] + pa) + wbv * tanh_fast(a11[r] + pb);
            sp2 += wa * tanh_fast(a02[r] + pa) + wbv * tanh_fast(a12[r] + pb);
            sp3 += wa * tanh_fast(a03[r] + pa) + wbv * tanh_fast(a13[r] + pb);
        }
        sp0 += __shfl_xor(sp0, 32); sp1 += __shfl_xor(sp1, 32);
        sp2 += __shfl_xor(sp2, 32); sp3 += __shfl_xor(sp3, 32);
        if (lane < 32) {
            red[wv][ 0 + lane] = sp0; red[wv][32 + lane] = sp1;
            red[wv][64 + lane] = sp2; red[wv][96 + lane] = sp3;
        }
        __syncthreads();

        if (wv == 0) {   // 128 scores: 2 per lane; chunk-local softmax
            float sa = 0.f, sb2 = 0.f;
#pragma unroll
            for (int q = 0; q < 8; ++q) { sa += red[q][lane]; sb2 += red[q][64 + lane]; }
            float m = fmaxf(sa, sb2);
#pragma unroll
            for (int off = 32; off; off >>= 1) m = fmaxf(m, __shfl_xor(m, off));
            float pa = __expf(sa - m), pb = __expf(sb2 - m);
            float d = pa + pb;
#pragma unroll
            for (int off = 32; off; off >>= 1) d += __shfl_xor(d, off);
            p_lds[lane] = pa; p_lds[64 + lane] = pb;
            if (lane == 0) { md[0] = m; md[1] = d; }
        }
        __syncthreads();

        // ---- online merge + ctx numerator (col-pair per thread, 64 rows) ----
        float m_c = md[0], d_c = md[1];
        float m_new = fmaxf(m_run, m_c);
        float so = __expf(m_run - m_new), sc = __expf(m_c - m_new);
        d_run = d_run * so + d_c * sc;
        float na = 0.f, nb = 0.f;
#pragma unroll 8
        for (int s2 = 0; s2 < 64; ++s2) {
            int s = h2 * 64 + s2;
            unsigned boff = ((unsigned)(s * 1024 + cp * 2)) ^ ((unsigned)(s & 7) << 4);
            unsigned u = *(const unsigned*)((const char*)ann_lds + boff);
            float p = p_lds[s];
            na += p * __uint_as_float(u << 16);
            nb += p * __uint_as_float(u & 0xFFFF0000u);
        }
        ctxa = ctxa * so + na * sc;
        ctxb = ctxb * so + nb * sc;
        m_run = m_new;
    }

    float* cb = cout + ((size_t)b * NSB + sb) * CH2;
    cb[2 + h2 * 512 + cp]     = ctxa;
    cb[2 + h2 * 512 + cp + 1] = ctxb;
    if (t == 0) { cb[0] = m_run; cb[1] = d_run; }
}

// ---- Kernel 4: merge 8 s-block partials per batch row ----
__global__ void finalize_ctx(const float* __restrict__ cout,
                             float* __restrict__ out) {
    int b = blockIdx.x, t = threadIdx.x;   // 512 threads
    float ms[NSB];
    float M = -3.0e38f;
#pragma unroll
    for (int s = 0; s < NSB; ++s) {
        ms[s] = cout[((size_t)b * NSB + s) * CH2];
        M = fmaxf(M, ms[s]);
    }
    float D = 0.f, val = 0.f;
#pragma unroll
    for (int s = 0; s < NSB; ++s) {
        const float* cb = cout + ((size_t)b * NSB + s) * CH2;
        float e = __expf(ms[s] - M);
        D += e * cb[1];
        val += e * (cb[2 + t] + cb[2 + 512 + t]);
    }
    out[(size_t)b * 512 + t] = val / D;
}

extern "C" void kernel_launch(void* const* d_in, const int* in_sizes, int n_in,
                              void* d_out, int out_size, void* d_ws, size_t ws_size,
                              hipStream_t stream) {
    (void)in_sizes; (void)n_in; (void)out_size; (void)ws_size;
    const float* prev = (const float*)d_in[0];
    const float* ann  = (const float*)d_in[1];
    const float* W1   = (const float*)d_in[2];
    const float* b1   = (const float*)d_in[3];
    const float* W2   = (const float*)d_in[4];
    // b2 (d_in[5]) cancels in softmax; unused.
    float* out = (float*)d_out;

    char* ws = (char*)d_ws;
    unsigned short* w1af = (unsigned short*)ws;               // 512*512*2 = 524288 B
    float* pre_part = (float*)(ws + 524288);                  // 32*4*512*4 = 262144 B
    float* cout     = (float*)(ws + 524288 + 262144);         // 32*8*1026*4 = 1050624 B

    build_w1af<<<dim3(8, 8), dim3(256), 0, stream>>>(W1, w1af);
    pre_partial<<<dim3(4, NB), dim3(256), 0, stream>>>(prev, W1, pre_part);
    score_ctx<<<dim3(NSB, NB), dim3(512), 0, stream>>>(ann, w1af, pre_part, b1, W2, cout);
    finalize_ctx<<<dim3(NB), dim3(512), 0, stream>>>(cout, out);
}